// Round 1
// baseline (492.514 us; speedup 1.0000x reference)
//
#include <hip/hip_runtime.h>
#include <math.h>

#define N_NODES 16384
#define N_EDGES 262144
#define HID 128
#define NRBF 20
#define CUTOFF 5.0f
#define PI_F 3.14159265358979323846f

// ---------------------------------------------------------------------------
// Kernel 1: phi = silu(s @ W1 + b1) @ W2 + b2     (N_NODES x 384) -> d_ws
// One block = 128 threads (thread = output channel t), NB nodes per block.
// ---------------------------------------------------------------------------
#define NB 16
__global__ __launch_bounds__(128) void phi_kernel(
    const float* __restrict__ s, const float* __restrict__ W1,
    const float* __restrict__ b1, const float* __restrict__ W2,
    const float* __restrict__ b2, float* __restrict__ phi)
{
    __shared__ float sL[NB][HID];
    __shared__ float hL[NB][HID];
    const int t = threadIdx.x;
    const int node0 = blockIdx.x * NB;

    #pragma unroll
    for (int i = 0; i < NB; ++i)
        sL[i][t] = s[(size_t)(node0 + i) * HID + t];
    __syncthreads();

    // phase 1: h = silu(s @ W1 + b1)
    float h[NB];
    const float bb1 = b1[t];
    #pragma unroll
    for (int i = 0; i < NB; ++i) h[i] = bb1;

    for (int k = 0; k < HID; k += 4) {
        float w[4];
        #pragma unroll
        for (int j = 0; j < 4; ++j) w[j] = W1[(size_t)(k + j) * HID + t];
        #pragma unroll
        for (int i = 0; i < NB; ++i) {
            const float4 sv = *reinterpret_cast<const float4*>(&sL[i][k]);
            h[i] += sv.x * w[0] + sv.y * w[1] + sv.z * w[2] + sv.w * w[3];
        }
    }
    #pragma unroll
    for (int i = 0; i < NB; ++i) {
        const float x = h[i];
        h[i] = x / (1.0f + expf(-x));      // silu
    }
    #pragma unroll
    for (int i = 0; i < NB; ++i) hL[i][t] = h[i];
    __syncthreads();

    // phase 2: phi = h @ W2 + b2   (thread t owns channels t, t+128, t+256)
    float a0[NB], a1[NB], a2[NB];
    #pragma unroll
    for (int i = 0; i < NB; ++i) { a0[i] = 0.f; a1[i] = 0.f; a2[i] = 0.f; }

    for (int k = 0; k < HID; k += 4) {
        float w0[4], w1[4], w2[4];
        #pragma unroll
        for (int j = 0; j < 4; ++j) {
            const size_t row = (size_t)(k + j) * 384;
            w0[j] = W2[row + t];
            w1[j] = W2[row + 128 + t];
            w2[j] = W2[row + 256 + t];
        }
        #pragma unroll
        for (int i = 0; i < NB; ++i) {
            const float4 hv = *reinterpret_cast<const float4*>(&hL[i][k]);
            a0[i] += hv.x * w0[0] + hv.y * w0[1] + hv.z * w0[2] + hv.w * w0[3];
            a1[i] += hv.x * w1[0] + hv.y * w1[1] + hv.z * w1[2] + hv.w * w1[3];
            a2[i] += hv.x * w2[0] + hv.y * w2[1] + hv.z * w2[2] + hv.w * w2[3];
        }
    }
    const float bb2a = b2[t], bb2b = b2[128 + t], bb2c = b2[256 + t];
    #pragma unroll
    for (int i = 0; i < NB; ++i) {
        const size_t row = (size_t)(node0 + i) * 384;
        phi[row + t]        = a0[i] + bb2a;
        phi[row + 128 + t]  = a1[i] + bb2b;
        phi[row + 256 + t]  = a2[i] + bb2c;
    }
}

// ---------------------------------------------------------------------------
// Kernel 2: per-edge RBF filter + gather + scatter-add (atomics).
// 128 threads per edge (thread = channel ch in [0,128)); block = 256 threads
// handles 2 edge lanes; grid-stride over edges so the 60 Wrbf registers are
// amortized over many edges.
// ---------------------------------------------------------------------------
__global__ __launch_bounds__(256) void edge_kernel(
    const float* __restrict__ v, const float* __restrict__ r_ij,
    const int* __restrict__ esrc, const int* __restrict__ edst,
    const float* __restrict__ Wrbf, const float* __restrict__ brbf,
    const float* __restrict__ phi,
    float* __restrict__ dv, float* __restrict__ ds)
{
    const int ch  = threadIdx.x & 127;
    const int sub = threadIdx.x >> 7;   // 0 or 1: which edge lane in the block

    // Per-thread Wrbf columns (registers, reused across all edges)
    float wr0[NRBF], wr1[NRBF], wr2[NRBF];
    #pragma unroll
    for (int n = 0; n < NRBF; ++n) {
        wr0[n] = Wrbf[n * 384 + ch];
        wr1[n] = Wrbf[n * 384 + 128 + ch];
        wr2[n] = Wrbf[n * 384 + 256 + ch];
    }
    const float br0 = brbf[ch], br1 = brbf[128 + ch], br2 = brbf[256 + ch];

    for (int e = blockIdx.x * 2 + sub; e < N_EDGES; e += gridDim.x * 2) {
        const int src = esrc[e];
        const int dst = edst[e];
        const float rx = r_ij[(size_t)e * 3 + 0];
        const float ry = r_ij[(size_t)e * 3 + 1];
        const float rz = r_ij[(size_t)e * 3 + 2];
        const float d2 = rx * rx + ry * ry + rz * rz;
        const float d  = sqrtf(d2);
        const float inv_d = 1.0f / d;
        const float x = (PI_F / CUTOFF) * d;
        float sx, cx;
        sincosf(x, &sx, &cx);
        const float fcut = (d < CUTOFF) ? 0.5f * (cx + 1.0f) : 0.0f;

        // rbf[n] = sin((n+1)*x)/d via Chebyshev recurrence
        float coef[NRBF];
        coef[0] = sx * inv_d;
        const float twocx = 2.0f * cx;
        float sm1 = sx, sm2 = 0.0f;
        #pragma unroll
        for (int n = 1; n < NRBF; ++n) {
            const float sn = twocx * sm1 - sm2;
            sm2 = sm1; sm1 = sn;
            coef[n] = sn * inv_d;
        }

        // W = (rbf @ Wrbf + brbf) * fcut    (3 channels per thread)
        float W0 = br0, W1v = br1, W2v = br2;
        #pragma unroll
        for (int n = 0; n < NRBF; ++n) {
            W0  += coef[n] * wr0[n];
            W1v += coef[n] * wr1[n];
            W2v += coef[n] * wr2[n];
        }
        W0 *= fcut; W1v *= fcut; W2v *= fcut;

        const size_t prow = (size_t)src * 384;
        const float x_vv  = phi[prow + ch]        * W0;
        const float x_s   = phi[prow + 128 + ch]  * W1v;
        const float x_dir = phi[prow + 256 + ch]  * W2v;

        const float ux = rx * inv_d, uy = ry * inv_d, uz = rz * inv_d;
        const float v0 = v[prow + ch];          // v has same (node,384) layout
        const float v1 = v[prow + 128 + ch];
        const float v2 = v[prow + 256 + ch];

        const size_t drow = (size_t)dst * 384;
        atomicAdd(&dv[drow + ch],        v0 * x_vv + ux * x_dir);
        atomicAdd(&dv[drow + 128 + ch],  v1 * x_vv + uy * x_dir);
        atomicAdd(&dv[drow + 256 + ch],  v2 * x_vv + uz * x_dir);
        atomicAdd(&ds[(size_t)dst * HID + ch], x_s);
    }
}

extern "C" void kernel_launch(void* const* d_in, const int* in_sizes, int n_in,
                              void* d_out, int out_size, void* d_ws, size_t ws_size,
                              hipStream_t stream)
{
    const float* s    = (const float*)d_in[0];
    const float* v    = (const float*)d_in[1];
    const float* r_ij = (const float*)d_in[2];
    const int*   esrc = (const int*)d_in[3];
    const int*   edst = (const int*)d_in[4];
    const float* W1   = (const float*)d_in[5];
    const float* b1   = (const float*)d_in[6];
    const float* W2   = (const float*)d_in[7];
    const float* b2   = (const float*)d_in[8];
    const float* Wrbf = (const float*)d_in[9];
    const float* brbf = (const float*)d_in[10];

    float* out = (float*)d_out;
    float* dv  = out;                                   // (16384,3,128)
    float* ds  = out + (size_t)N_NODES * 3 * HID;       // (16384,128)
    float* phi = (float*)d_ws;                          // (16384,384) = 25 MB

    hipMemsetAsync(d_out, 0, (size_t)out_size * sizeof(float), stream);

    phi_kernel<<<N_NODES / NB, 128, 0, stream>>>(s, W1, b1, W2, b2, phi);
    edge_kernel<<<8192, 256, 0, stream>>>(v, r_ij, esrc, edst, Wrbf, brbf,
                                          phi, dv, ds);
}

// Round 2
// 300.689 us; speedup vs baseline: 1.6379x; 1.6379x over previous
//
#include <hip/hip_runtime.h>
#include <math.h>

#define N_NODES 16384
#define N_EDGES 262144
#define HID 128
#define NRBF 20
#define CUTOFF 5.0f
#define PI_F 3.14159265358979323846f

// record layout (28 floats = 112 B, 16B aligned):
// [0]=src(int bits) [1]=fcut [2]=ux [3]=uy [4]=uz [5..7]=pad [8..27]=cf[20]
#define REC_STRIDE 28

// ---------------------------------------------------------------------------
// Kernel 1: phi = silu(s @ W1 + b1) @ W2 + b2     (N_NODES x 384) -> ws
// ---------------------------------------------------------------------------
#define NB 16
__global__ __launch_bounds__(128) void phi_kernel(
    const float* __restrict__ s, const float* __restrict__ W1,
    const float* __restrict__ b1, const float* __restrict__ W2,
    const float* __restrict__ b2, float* __restrict__ phi)
{
    __shared__ float sL[NB][HID];
    __shared__ float hL[NB][HID];
    const int t = threadIdx.x;
    const int node0 = blockIdx.x * NB;

    #pragma unroll
    for (int i = 0; i < NB; ++i)
        sL[i][t] = s[(size_t)(node0 + i) * HID + t];
    __syncthreads();

    float h[NB];
    const float bb1 = b1[t];
    #pragma unroll
    for (int i = 0; i < NB; ++i) h[i] = bb1;

    for (int k = 0; k < HID; k += 4) {
        float w[4];
        #pragma unroll
        for (int j = 0; j < 4; ++j) w[j] = W1[(size_t)(k + j) * HID + t];
        #pragma unroll
        for (int i = 0; i < NB; ++i) {
            const float4 sv = *reinterpret_cast<const float4*>(&sL[i][k]);
            h[i] += sv.x * w[0] + sv.y * w[1] + sv.z * w[2] + sv.w * w[3];
        }
    }
    #pragma unroll
    for (int i = 0; i < NB; ++i) {
        const float x = h[i];
        h[i] = x / (1.0f + expf(-x));
    }
    #pragma unroll
    for (int i = 0; i < NB; ++i) hL[i][t] = h[i];
    __syncthreads();

    float a0[NB], a1[NB], a2[NB];
    #pragma unroll
    for (int i = 0; i < NB; ++i) { a0[i] = 0.f; a1[i] = 0.f; a2[i] = 0.f; }

    for (int k = 0; k < HID; k += 4) {
        float w0[4], w1[4], w2[4];
        #pragma unroll
        for (int j = 0; j < 4; ++j) {
            const size_t row = (size_t)(k + j) * 384;
            w0[j] = W2[row + t];
            w1[j] = W2[row + 128 + t];
            w2[j] = W2[row + 256 + t];
        }
        #pragma unroll
        for (int i = 0; i < NB; ++i) {
            const float4 hv = *reinterpret_cast<const float4*>(&hL[i][k]);
            a0[i] += hv.x * w0[0] + hv.y * w0[1] + hv.z * w0[2] + hv.w * w0[3];
            a1[i] += hv.x * w1[0] + hv.y * w1[1] + hv.z * w1[2] + hv.w * w1[3];
            a2[i] += hv.x * w2[0] + hv.y * w2[1] + hv.z * w2[2] + hv.w * w2[3];
        }
    }
    const float bb2a = b2[t], bb2b = b2[128 + t], bb2c = b2[256 + t];
    #pragma unroll
    for (int i = 0; i < NB; ++i) {
        const size_t row = (size_t)(node0 + i) * 384;
        phi[row + t]        = a0[i] + bb2a;
        phi[row + 128 + t]  = a1[i] + bb2b;
        phi[row + 256 + t]  = a2[i] + bb2c;
    }
}

// ---------------------------------------------------------------------------
// CSR build: histogram -> scan -> scatter records
// ---------------------------------------------------------------------------
__global__ __launch_bounds__(256) void hist_kernel(const int* __restrict__ edst,
                                                   int* __restrict__ cnt)
{
    const int e = blockIdx.x * 256 + threadIdx.x;
    if (e < N_EDGES) atomicAdd(&cnt[edst[e]], 1);
}

__global__ __launch_bounds__(256) void scan_kernel(const int* __restrict__ cnt,
                                                   int* __restrict__ row_ptr,
                                                   int* __restrict__ cur)
{
    __shared__ int part[256];
    const int tid = threadIdx.x;
    const int4* c4 = (const int4*)cnt;

    int4 loc[16];
    int s = 0;
    #pragma unroll
    for (int j = 0; j < 16; ++j) {
        loc[j] = c4[tid * 16 + j];
        s += loc[j].x + loc[j].y + loc[j].z + loc[j].w;
    }
    part[tid] = s;
    __syncthreads();
    #pragma unroll
    for (int d = 1; d < 256; d <<= 1) {
        const int add = (tid >= d) ? part[tid - d] : 0;
        __syncthreads();
        part[tid] += add;
        __syncthreads();
    }
    int off = (tid == 0) ? 0 : part[tid - 1];
    const int base = tid * 64;
    #pragma unroll
    for (int j = 0; j < 16; ++j) {
        const int4 q = loc[j];
        row_ptr[base + j*4 + 0] = off; cur[base + j*4 + 0] = off; off += q.x;
        row_ptr[base + j*4 + 1] = off; cur[base + j*4 + 1] = off; off += q.y;
        row_ptr[base + j*4 + 2] = off; cur[base + j*4 + 2] = off; off += q.z;
        row_ptr[base + j*4 + 3] = off; cur[base + j*4 + 3] = off; off += q.w;
    }
    if (tid == 255) row_ptr[16384] = off;
}

__global__ __launch_bounds__(256) void scatter_kernel(
    const float* __restrict__ r_ij, const int* __restrict__ esrc,
    const int* __restrict__ edst, int* __restrict__ cur,
    float* __restrict__ rec)
{
    const int e = blockIdx.x * 256 + threadIdx.x;
    if (e >= N_EDGES) return;
    const float rx = r_ij[(size_t)e * 3 + 0];
    const float ry = r_ij[(size_t)e * 3 + 1];
    const float rz = r_ij[(size_t)e * 3 + 2];
    const float d = sqrtf(rx * rx + ry * ry + rz * rz);
    const float inv_d = 1.0f / d;
    float sx, cx;
    sincosf((PI_F / CUTOFF) * d, &sx, &cx);
    const float fcut = (d < CUTOFF) ? 0.5f * (cx + 1.0f) : 0.0f;

    float cf[NRBF];
    const float g = inv_d * fcut;     // fold 1/d and fcut into the rbf coefs
    const float twocx = 2.0f * cx;
    float sm1 = sx, sm2 = 0.0f;
    cf[0] = sx * g;
    #pragma unroll
    for (int n = 1; n < NRBF; ++n) {
        const float sn = twocx * sm1 - sm2;
        sm2 = sm1; sm1 = sn;
        cf[n] = sn * g;
    }

    const int pos = atomicAdd(&cur[edst[e]], 1);
    float4* r4 = (float4*)(rec + (size_t)pos * REC_STRIDE);
    r4[0] = make_float4(__int_as_float(esrc[e]), fcut, rx * inv_d, ry * inv_d);
    r4[1] = make_float4(rz * inv_d, 0.f, 0.f, 0.f);
    r4[2] = make_float4(cf[0],  cf[1],  cf[2],  cf[3]);
    r4[3] = make_float4(cf[4],  cf[5],  cf[6],  cf[7]);
    r4[4] = make_float4(cf[8],  cf[9],  cf[10], cf[11]);
    r4[5] = make_float4(cf[12], cf[13], cf[14], cf[15]);
    r4[6] = make_float4(cf[16], cf[17], cf[18], cf[19]);
}

// ---------------------------------------------------------------------------
// Gather: one 128-thread lane-group per node, accumulate in registers,
// write outputs exactly once. No atomics.
// ---------------------------------------------------------------------------
__global__ __launch_bounds__(256) void gather_kernel(
    const float* __restrict__ v, const float* __restrict__ phi,
    const float* __restrict__ rec, const int* __restrict__ row_ptr,
    const float* __restrict__ Wrbf, const float* __restrict__ brbf,
    float* __restrict__ dv, float* __restrict__ ds)
{
    const int ch   = threadIdx.x & 127;
    const int node = blockIdx.x * 2 + (threadIdx.x >> 7);

    float wr0[NRBF], wr1[NRBF], wr2[NRBF];
    #pragma unroll
    for (int n = 0; n < NRBF; ++n) {
        wr0[n] = Wrbf[n * 384 + ch];
        wr1[n] = Wrbf[n * 384 + 128 + ch];
        wr2[n] = Wrbf[n * 384 + 256 + ch];
    }
    const float br0 = brbf[ch], br1 = brbf[128 + ch], br2 = brbf[256 + ch];

    const int beg = row_ptr[node];
    const int end = row_ptr[node + 1];

    float a0 = 0.f, a1 = 0.f, a2 = 0.f, asum = 0.f;

    for (int i = beg; i < end; ++i) {
        const float4* r4 = (const float4*)(rec + (size_t)i * REC_STRIDE);
        const float4 q0 = r4[0];
        const float4 q1 = r4[1];
        const float4 q2 = r4[2];
        const float4 q3 = r4[3];
        const float4 q4 = r4[4];
        const float4 q5 = r4[5];
        const float4 q6 = r4[6];
        const int   src  = __float_as_int(q0.x);
        const float fcut = q0.y, ux = q0.z, uy = q0.w, uz = q1.x;

        const float c[NRBF] = { q2.x, q2.y, q2.z, q2.w,
                                q3.x, q3.y, q3.z, q3.w,
                                q4.x, q4.y, q4.z, q4.w,
                                q5.x, q5.y, q5.z, q5.w,
                                q6.x, q6.y, q6.z, q6.w };

        float W0 = br0 * fcut, W1v = br1 * fcut, W2v = br2 * fcut;
        #pragma unroll
        for (int n = 0; n < NRBF; ++n) {
            W0  += c[n] * wr0[n];
            W1v += c[n] * wr1[n];
            W2v += c[n] * wr2[n];
        }

        const size_t prow = (size_t)src * 384;
        const float x_vv  = phi[prow + ch]       * W0;
        const float x_s   = phi[prow + 128 + ch] * W1v;
        const float x_dir = phi[prow + 256 + ch] * W2v;

        a0   += v[prow + ch]       * x_vv + ux * x_dir;
        a1   += v[prow + 128 + ch] * x_vv + uy * x_dir;
        a2   += v[prow + 256 + ch] * x_vv + uz * x_dir;
        asum += x_s;
    }

    const size_t orow = (size_t)node * 384;
    dv[orow + ch]       = a0;
    dv[orow + 128 + ch] = a1;
    dv[orow + 256 + ch] = a2;
    ds[(size_t)node * HID + ch] = asum;
}

extern "C" void kernel_launch(void* const* d_in, const int* in_sizes, int n_in,
                              void* d_out, int out_size, void* d_ws, size_t ws_size,
                              hipStream_t stream)
{
    const float* s    = (const float*)d_in[0];
    const float* v    = (const float*)d_in[1];
    const float* r_ij = (const float*)d_in[2];
    const int*   esrc = (const int*)d_in[3];
    const int*   edst = (const int*)d_in[4];
    const float* W1   = (const float*)d_in[5];
    const float* b1   = (const float*)d_in[6];
    const float* W2   = (const float*)d_in[7];
    const float* b2   = (const float*)d_in[8];
    const float* Wrbf = (const float*)d_in[9];
    const float* brbf = (const float*)d_in[10];

    float* out = (float*)d_out;
    float* dv  = out;                                   // (16384,3,128)
    float* ds  = out + (size_t)N_NODES * 3 * HID;       // (16384,128)

    // workspace layout (all 16B aligned)
    char* ws = (char*)d_ws;
    float* phi     = (float*)(ws + 0);                  // 25,165,824 B
    float* rec     = (float*)(ws + 25165824);           // 29,360,128 B
    int*   cnt     = (int*)  (ws + 54525952);           // 65,536 B
    int*   row_ptr = (int*)  (ws + 54591488);           // 65,540 B (+pad)
    int*   cur     = (int*)  (ws + 54657152);           // 65,536 B

    hipMemsetAsync(cnt, 0, 16384 * sizeof(int), stream);

    phi_kernel<<<N_NODES / NB, 128, 0, stream>>>(s, W1, b1, W2, b2, phi);
    hist_kernel<<<N_EDGES / 256, 256, 0, stream>>>(edst, cnt);
    scan_kernel<<<1, 256, 0, stream>>>(cnt, row_ptr, cur);
    scatter_kernel<<<N_EDGES / 256, 256, 0, stream>>>(r_ij, esrc, edst, cur, rec);
    gather_kernel<<<N_NODES / 2, 256, 0, stream>>>(v, phi, rec, row_ptr,
                                                   Wrbf, brbf, dv, ds);
}